// Round 6
// baseline (238.480 us; speedup 1.0000x reference)
//
#include <hip/hip_runtime.h>
#include <hip/hip_bf16.h>

// Sobel edge detection, promote: x[32,3,512,512] f32 -> edge[32,1,512,512] f32 (0/1)
// grad_x = cross-corr with [[-1,0,1],[-2,0,2],[-1,0,1]] (depthwise, per channel)
// grad_y = cross-corr with [[-1,-2,-1],[0,0,0],[1,2,1]]
// edge = OR_c ( sqrt(gx^2+gy^2) > 0.2 ) = ( sqrtf( max_c(gx^2+gy^2) ) > 0.2 )
//
// ROUND 3 LESSON (measured): 4x8 tile -> 160 VGPR -> OccupancyPercent 9.8%,
// 17% HBM BW, VALUBusy 23% => latency/occupancy-bound, NOT bandwidth-bound
// (FETCH 56.6MB < input 100.7MB: L3 absorbs; WRITE 33.5MB = ideal).
// THIS ROUND (untested so far due to broker timeouts): lean 2x4 tile
// (~38 live floats), rolling 3-row separable buffer, deferred sqrt,
// __launch_bounds__(256,6) caps VGPR ~85 -> ~6 waves/SIMD, 4096 blocks.

#define H 512
#define W 512
#define C 3
#define B 32

__global__ __launch_bounds__(256, 6) void sobel_edge_kernel(
    const float* __restrict__ x, float* __restrict__ out) {
    // tid -> (b, hq, wq): wq in [0,128) (4-col groups), hq in [0,256) (2-row groups)
    const int tid = blockIdx.x * blockDim.x + threadIdx.x;
    const int wq = tid & 127;
    const int hq = (tid >> 7) & 255;
    const int b  = tid >> 15;          // 128*256 = 2^15 threads per image

    const int w0 = wq << 2;
    const int h0 = hq << 1;
    const bool has_left  = (w0 > 0);
    const bool has_right = (w0 + 4 < W);
    const float* xb = x + (size_t)b * C * H * W;

    // running max over channels of gx^2+gy^2, per output pixel
    float smax[2][4];
#pragma unroll
    for (int i = 0; i < 2; ++i)
#pragma unroll
        for (int j = 0; j < 4; ++j) smax[i][j] = 0.0f;

#pragma unroll
    for (int c = 0; c < C; ++c) {
        const float* xc = xb + (size_t)c * H * W;

        float dxb[3][4], sxb[3][4];   // rolling 3-row buffers (static idx only)

#pragma unroll
        for (int r = 0; r < 4; ++r) {
            // ---- load input row h0-1+r, cols w0-1 .. w0+4 ----
            float p[6];
            const int hh = h0 + r - 1;
            if (hh >= 0 && hh < H) {     // wave-uniform (h0 uniform per wave half)
                const float* rp = xc + (size_t)hh * W;
                const float4 m = *reinterpret_cast<const float4*>(rp + w0);
                p[1] = m.x; p[2] = m.y; p[3] = m.z; p[4] = m.w;
                p[0] = has_left  ? rp[w0 - 1] : 0.0f;
                p[5] = has_right ? rp[w0 + 4] : 0.0f;
            } else {
#pragma unroll
                for (int k = 0; k < 6; ++k) p[k] = 0.0f;
            }

            // ---- row-wise separable intermediates into rolling slot ----
            const int rr = r % 3;      // compile-time (fully unrolled)
#pragma unroll
            for (int j = 0; j < 4; ++j) {
                dxb[rr][j] = p[j + 2] - p[j];
                sxb[rr][j] = p[j] + 2.0f * p[j + 1] + p[j + 2];
            }

            // ---- once 3 rows live, emit output row i = r-2 ----
            if (r >= 2) {
                const int i  = r - 2;
                const int r0 = (r - 2) % 3;
                const int r1 = (r - 1) % 3;
                const int r2 = rr;
#pragma unroll
                for (int j = 0; j < 4; ++j) {
                    const float gx = dxb[r0][j] + 2.0f * dxb[r1][j] + dxb[r2][j];
                    const float gy = sxb[r2][j] - sxb[r0][j];
                    const float s  = gx * gx + gy * gy;
                    smax[i][j] = fmaxf(smax[i][j], s);
                }
            }
        }
    }

    // ---- threshold + store (1 float4 per output row) ----
    float* ob = out + ((size_t)b * H + h0) * W + w0;
#pragma unroll
    for (int i = 0; i < 2; ++i) {
        float4 o;
        o.x = (sqrtf(smax[i][0]) > 0.2f) ? 1.0f : 0.0f;
        o.y = (sqrtf(smax[i][1]) > 0.2f) ? 1.0f : 0.0f;
        o.z = (sqrtf(smax[i][2]) > 0.2f) ? 1.0f : 0.0f;
        o.w = (sqrtf(smax[i][3]) > 0.2f) ? 1.0f : 0.0f;
        *reinterpret_cast<float4*>(ob + (size_t)i * W) = o;
    }
}

extern "C" void kernel_launch(void* const* d_in, const int* in_sizes, int n_in,
                              void* d_out, int out_size, void* d_ws, size_t ws_size,
                              hipStream_t stream) {
    const float* x = (const float*)d_in[0];
    float* out = (float*)d_out;
    // total threads = 32 * 256 * 128 = 1,048,576 -> 4096 blocks of 256
    const int total = B * (H / 2) * (W / 4);
    const int block = 256;
    const int grid = total / block;  // exact
    sobel_edge_kernel<<<grid, block, 0, stream>>>(x, out);
}

// Round 11
// 153.738 us; speedup vs baseline: 1.5512x; 1.5512x over previous
//
#include <hip/hip_runtime.h>
#include <hip/hip_bf16.h>

// Sobel edge detection, promote: x[32,3,512,512] f32 -> edge[32,1,512,512] f32 (0/1)
// grad_x = cross-corr with [[-1,0,1],[-2,0,2],[-1,0,1]] (depthwise, per channel)
// grad_y = cross-corr with [[-1,-2,-1],[0,0,0],[1,2,1]]
// edge = OR_c ( sqrt(gx^2+gy^2) > 0.2 ) = ( sqrtf( max_c(gx^2+gy^2) ) > 0.2 )
//
// MEASURED LADDER:
//  R3: 4x8 tile, 160 VGPR, no bounds -> 3 waves/SIMD, Occ 9.8%, 17% HBM, 64 us
//      (latency-bound; FETCH 56.6MB L3-absorbed, WRITE 33.5MB ideal)
//  R6: 2x4 tile, __launch_bounds__(256,6) -> VGPR forced to 40 -> SPILLS:
//      WRITE_SIZE 240MB (!), FETCH 183MB, Occ 60% but dur 132 us. Regression.
//  R10 (5th resubmit; infra failures R7-R10): same 2x4 tile,
//      __launch_bounds__(256,4) -> VGPR cap 128 (>= natural ~60, cannot
//      force spills; only prevents balloon to 160). Expect 4+ waves/SIMD,
//      WRITE back to 33.5MB. Spill detector: WRITE_SIZE.

#define H 512
#define W 512
#define C 3
#define B 32

__global__ __launch_bounds__(256, 4) void sobel_edge_kernel(
    const float* __restrict__ x, float* __restrict__ out) {
    // tid -> (b, hq, wq): wq in [0,128) (4-col groups), hq in [0,256) (2-row groups)
    const int tid = blockIdx.x * blockDim.x + threadIdx.x;
    const int wq = tid & 127;
    const int hq = (tid >> 7) & 255;
    const int b  = tid >> 15;          // 128*256 = 2^15 threads per image

    const int w0 = wq << 2;
    const int h0 = hq << 1;
    const bool has_left  = (w0 > 0);
    const bool has_right = (w0 + 4 < W);
    const float* xb = x + (size_t)b * C * H * W;

    // running max over channels of gx^2+gy^2, per output pixel
    float smax[2][4];
#pragma unroll
    for (int i = 0; i < 2; ++i)
#pragma unroll
        for (int j = 0; j < 4; ++j) smax[i][j] = 0.0f;

#pragma unroll
    for (int c = 0; c < C; ++c) {
        const float* xc = xb + (size_t)c * H * W;

        float dxb[3][4], sxb[3][4];   // rolling 3-row buffers (static idx only)

#pragma unroll
        for (int r = 0; r < 4; ++r) {
            // ---- load input row h0-1+r, cols w0-1 .. w0+4 ----
            float p[6];
            const int hh = h0 + r - 1;
            if (hh >= 0 && hh < H) {
                const float* rp = xc + (size_t)hh * W;
                const float4 m = *reinterpret_cast<const float4*>(rp + w0);
                p[1] = m.x; p[2] = m.y; p[3] = m.z; p[4] = m.w;
                p[0] = has_left  ? rp[w0 - 1] : 0.0f;
                p[5] = has_right ? rp[w0 + 4] : 0.0f;
            } else {
#pragma unroll
                for (int k = 0; k < 6; ++k) p[k] = 0.0f;
            }

            // ---- row-wise separable intermediates into rolling slot ----
            const int rr = r % 3;      // compile-time (fully unrolled)
#pragma unroll
            for (int j = 0; j < 4; ++j) {
                dxb[rr][j] = p[j + 2] - p[j];
                sxb[rr][j] = p[j] + 2.0f * p[j + 1] + p[j + 2];
            }

            // ---- once 3 rows live, emit output row i = r-2 ----
            if (r >= 2) {
                const int i  = r - 2;
                const int r0 = (r - 2) % 3;
                const int r1 = (r - 1) % 3;
                const int r2 = rr;
#pragma unroll
                for (int j = 0; j < 4; ++j) {
                    const float gx = dxb[r0][j] + 2.0f * dxb[r1][j] + dxb[r2][j];
                    const float gy = sxb[r2][j] - sxb[r0][j];
                    const float s  = gx * gx + gy * gy;
                    smax[i][j] = fmaxf(smax[i][j], s);
                }
            }
        }
    }

    // ---- threshold + store (1 float4 per output row) ----
    float* ob = out + ((size_t)b * H + h0) * W + w0;
#pragma unroll
    for (int i = 0; i < 2; ++i) {
        float4 o;
        o.x = (sqrtf(smax[i][0]) > 0.2f) ? 1.0f : 0.0f;
        o.y = (sqrtf(smax[i][1]) > 0.2f) ? 1.0f : 0.0f;
        o.z = (sqrtf(smax[i][2]) > 0.2f) ? 1.0f : 0.0f;
        o.w = (sqrtf(smax[i][3]) > 0.2f) ? 1.0f : 0.0f;
        *reinterpret_cast<float4*>(ob + (size_t)i * W) = o;
    }
}

extern "C" void kernel_launch(void* const* d_in, const int* in_sizes, int n_in,
                              void* d_out, int out_size, void* d_ws, size_t ws_size,
                              hipStream_t stream) {
    const float* x = (const float*)d_in[0];
    float* out = (float*)d_out;
    // total threads = 32 * 256 * 128 = 1,048,576 -> 4096 blocks of 256
    const int total = B * (H / 2) * (W / 4);
    const int block = 256;
    const int grid = total / block;  // exact
    sobel_edge_kernel<<<grid, block, 0, stream>>>(x, out);
}